// Round 4
// baseline (5177.161 us; speedup 1.0000x reference)
//
#include <hip/hip_runtime.h>
#include <math.h>

// Problem constants (fixed by the reference)
constexpr int B_ = 32, T_ = 2048, E_ = 512, F_ = 512, KW = 7, H_ = 8;
constexpr float EPS_ = 1e-5f;

typedef unsigned short bfu;   // raw bf16 bits (internal workspace format)

__device__ __forceinline__ float b2f(bfu u) {
    return __uint_as_float(((unsigned)u) << 16);
}
__device__ __forceinline__ bfu f2b(float f) {
    unsigned i = __float_as_uint(f);
    i += 0x7fffu + ((i >> 16) & 1u);   // round-to-nearest-even
    return (bfu)(i >> 16);
}

template <typename T> __device__ __forceinline__ void stv(T* p, size_t i, float v);
template <> __device__ __forceinline__ void stv<bfu>(bfu* p, size_t i, float v)   { p[i] = f2b(v); }
template <> __device__ __forceinline__ void stv<float>(float* p, size_t i, float v) { p[i] = v; }

// ---------------------------------------------------------------------------
__global__ void zero_kernel(float* p, int n) {
    int i = blockIdx.x * 256 + threadIdx.x;
    if (i < n) p[i] = 0.f;
}

// ---------------------------------------------------------------------------
// x (B,T,E) fp32 -> x0 (B,E,T) bf16, adding pe[b,e] (pos-enc over the BATCH
// dim, faithful to the reference's pe[:x.size(0)] quirk).
__global__ void pos_transpose(const float* __restrict__ x, bfu* __restrict__ x0) {
    __shared__ float tile[32][33];
    int b  = blockIdx.z;
    int t0 = blockIdx.x * 32;
    int e0 = blockIdx.y * 32;
    int tx = threadIdx.x, ty = threadIdx.y;
    for (int i = ty; i < 32; i += 8)
        tile[i][tx] = x[((size_t)b * T_ + t0 + i) * E_ + e0 + tx];
    __syncthreads();
    for (int i = ty; i < 32; i += 8) {
        int e = e0 + i;
        float div = expf(-(float)(e & ~1) * (logf(10000.0f) / (float)E_));
        float ang = (float)b * div;
        float pe  = (e & 1) ? cosf(ang) : sinf(ang);
        x0[((size_t)b * E_ + e) * T_ + t0 + tx] = f2b(tile[tx][i] + pe);
    }
}

// ---------------------------------------------------------------------------
// LN stats: fp32 sum & sumsq per contiguous group of L bf16 elements.
__global__ __launch_bounds__(256) void ln_stats(const bfu* __restrict__ x,
                                                float* __restrict__ stats,
                                                int L, int slices) {
    int g = blockIdx.y, s = blockIdx.x;
    int chunk = L / slices;
    const ushort4* p = (const ushort4*)(x + (size_t)g * L + (size_t)s * chunk);
    int n4 = chunk >> 2;
    float sum = 0.f, sq = 0.f;
    for (int i = threadIdx.x; i < n4; i += 256) {
        ushort4 v = p[i];
        float a = b2f(v.x), b = b2f(v.y), c = b2f(v.z), d = b2f(v.w);
        sum += a + b + c + d;
        sq  += a * a + b * b + c * c + d * d;
    }
    #pragma unroll
    for (int off = 32; off > 0; off >>= 1) {
        sum += __shfl_down(sum, off, 64);
        sq  += __shfl_down(sq,  off, 64);
    }
    __shared__ float ss[8];
    int lane = threadIdx.x & 63, wid = threadIdx.x >> 6;
    if (lane == 0) { ss[wid] = sum; ss[4 + wid] = sq; }
    __syncthreads();
    if (threadIdx.x == 0) {
        atomicAdd(&stats[2 * g],     ss[0] + ss[1] + ss[2] + ss[3]);
        atomicAdd(&stats[2 * g + 1], ss[4] + ss[5] + ss[6] + ss[7]);
    }
}

__device__ __forceinline__ float ln_rstd(float sumsq, float mu, float invL) {
    float var = fmaxf(sumsq * invL - mu * mu, 0.f);
    return rsqrtf(var + EPS_);
}

// ---------------------------------------------------------------------------
// Depthwise conv (K=7, pad 3) with LN applied on the fly; x (B,C,T) bf16,
// fp32 weights/bias, per-batch stats. Padding zeros live in LN space.
__global__ __launch_bounds__(256) void dwconv_ln(const bfu* __restrict__ x,
                                                 const float* __restrict__ stats,
                                                 const float* __restrict__ w,
                                                 const float* __restrict__ bias,
                                                 bfu* __restrict__ out) {
    int t = blockIdx.x * 256 + threadIdx.x;
    int c = blockIdx.y, b = blockIdx.z;
    const float invL = 1.0f / (float)(F_ * T_);
    float mu   = stats[2 * b] * invL;
    float rstd = ln_rstd(stats[2 * b + 1], mu, invL);
    const bfu* xr = x + ((size_t)b * F_ + c) * T_;
    float acc = bias[c];
    #pragma unroll
    for (int k = 0; k < KW; k++) {
        int tt = t + k - KW / 2;
        if (tt >= 0 && tt < T_)
            acc += w[c * KW + k] * ((b2f(xr[tt]) - mu) * rstd);
    }
    out[((size_t)b * F_ + c) * T_ + t] = f2b(acc);
}

// ---------------------------------------------------------------------------
// Pointwise conv as per-batch GEMM: out[b,m,n] = sum_k W[m,k]*X[b,k,n] + bias[m]
// (+ res[b,m,n]). W/bias fp32; X/res/out bf16; fp32 LDS tiles + fp32 accum.
__global__ __launch_bounds__(256) void gemm_pw(const float* __restrict__ W,
                                               const bfu* __restrict__ X,
                                               const float* __restrict__ bias,
                                               const bfu* res, bfu* out) {
    constexpr int M = F_, N = T_, Kd = F_;
    __shared__ __align__(16) float As[16][68];  // [k][m]
    __shared__ __align__(16) float Bs[16][68];  // [k][n]
    int b  = blockIdx.z;
    int n0 = blockIdx.x * 64, m0 = blockIdx.y * 64;
    const bfu* Xb   = X + (size_t)b * Kd * N;
    bfu*       outb = out + (size_t)b * M * N;
    const bfu* resb = res ? res + (size_t)b * M * N : nullptr;
    int tid = threadIdx.x;
    int wr = tid >> 2, wk4 = (tid & 3) * 4;
    int xr = tid >> 4, xn4 = (tid & 15) * 4;
    int ty = tid >> 4, tx = tid & 15;
    float acc[4][4] = {};
    for (int k0 = 0; k0 < Kd; k0 += 16) {
        float4  wv = *(const float4*)(W   + (size_t)(m0 + wr) * Kd + k0 + wk4);
        ushort4 xv = *(const ushort4*)(Xb + (size_t)(k0 + xr) * N  + n0 + xn4);
        As[wk4 + 0][wr] = wv.x;
        As[wk4 + 1][wr] = wv.y;
        As[wk4 + 2][wr] = wv.z;
        As[wk4 + 3][wr] = wv.w;
        Bs[xr][xn4 + 0] = b2f(xv.x);
        Bs[xr][xn4 + 1] = b2f(xv.y);
        Bs[xr][xn4 + 2] = b2f(xv.z);
        Bs[xr][xn4 + 3] = b2f(xv.w);
        __syncthreads();
        #pragma unroll
        for (int k = 0; k < 16; k++) {
            float4 a  = *(const float4*)(&As[k][ty * 4]);
            float4 bb = *(const float4*)(&Bs[k][tx * 4]);
            acc[0][0] += a.x * bb.x; acc[0][1] += a.x * bb.y; acc[0][2] += a.x * bb.z; acc[0][3] += a.x * bb.w;
            acc[1][0] += a.y * bb.x; acc[1][1] += a.y * bb.y; acc[1][2] += a.y * bb.z; acc[1][3] += a.y * bb.w;
            acc[2][0] += a.z * bb.x; acc[2][1] += a.z * bb.y; acc[2][2] += a.z * bb.z; acc[2][3] += a.z * bb.w;
            acc[3][0] += a.w * bb.x; acc[3][1] += a.w * bb.y; acc[3][2] += a.w * bb.z; acc[3][3] += a.w * bb.w;
        }
        __syncthreads();
    }
    #pragma unroll
    for (int i = 0; i < 4; i++) {
        int m = m0 + ty * 4 + i;
        float bv = bias[m];
        #pragma unroll
        for (int j = 0; j < 4; j++) {
            int n = n0 + tx * 4 + j;
            size_t idx = (size_t)m * N + n;
            float v = acc[i][j] + bv;
            if (resb) v += b2f(resb[idx]);
            outb[idx] = f2b(v);
        }
    }
}

// ---------------------------------------------------------------------------
// x (B,F,T) bf16 -> xa[t,b,f] = x[b,f,t]; yln = LN-applied copy (per-b stats).
__global__ void transpose_ln(const bfu* __restrict__ x, const float* __restrict__ stats,
                             bfu* __restrict__ xa, bfu* __restrict__ yln) {
    __shared__ float tile[32][33];
    int b  = blockIdx.z;
    int t0 = blockIdx.x * 32, f0 = blockIdx.y * 32;
    const float invL = 1.0f / (float)(F_ * T_);
    float mu   = stats[2 * b] * invL;
    float rstd = ln_rstd(stats[2 * b + 1], mu, invL);
    int tx = threadIdx.x, ty = threadIdx.y;
    for (int i = ty; i < 32; i += 8)
        tile[i][tx] = b2f(x[((size_t)b * F_ + f0 + i) * T_ + t0 + tx]);
    __syncthreads();
    for (int i = ty; i < 32; i += 8) {
        int t = t0 + i, f = f0 + tx;
        float v = tile[tx][i];
        size_t idx = ((size_t)t * B_ + b) * F_ + f;
        xa[idx]  = f2b(v);
        yln[idx] = f2b((v - mu) * rstd);
    }
}

// ---------------------------------------------------------------------------
// NT GEMM: out[r,m] = sum_k A[r,k]*W[m,k] + bias[m] (+res[r,m]).
// A/res bf16, W/bias fp32, out templated (bf16 internal / fp32 final).
// Optional fused LN of A rows (group = r>>5, i.e. per t over (B,F)).
// out_transpose=1 writes out[((r&31)*T + (r>>5))*F + m] (final (B,T,F)).
template <typename OutT>
__global__ __launch_bounds__(256) void gemm_nt(const bfu* __restrict__ A,
                                               const float* __restrict__ W,
                                               const float* __restrict__ bias,
                                               const bfu* res, OutT* out,
                                               const float* __restrict__ lnst,
                                               float ln_inv, int out_transpose) {
    constexpr int M = F_, Kd = F_;
    __shared__ __align__(16) float As[16][68];
    __shared__ __align__(16) float Ws[16][68];
    int m0 = blockIdx.x * 64;
    int r0 = blockIdx.y * 64;
    int tid = threadIdx.x;
    int lr = tid >> 2, lk4 = (tid & 3) * 4;
    int ty = tid >> 4, tx = tid & 15;
    float mu = 0.f, rstd = 1.f;
    if (lnst) {
        int g = (r0 + lr) >> 5;
        float m_ = lnst[2 * g] * ln_inv;
        mu = m_; rstd = ln_rstd(lnst[2 * g + 1], m_, ln_inv);
    }
    float acc[4][4] = {};
    for (int k0 = 0; k0 < Kd; k0 += 16) {
        ushort4 av4 = *(const ushort4*)(A + (size_t)(r0 + lr) * Kd + k0 + lk4);
        float4  wv4 = *(const float4*)(W  + (size_t)(m0 + lr) * Kd + k0 + lk4);
        float ax = b2f(av4.x), ay = b2f(av4.y), az = b2f(av4.z), aw = b2f(av4.w);
        if (lnst) {
            ax = (ax - mu) * rstd; ay = (ay - mu) * rstd;
            az = (az - mu) * rstd; aw = (aw - mu) * rstd;
        }
        As[lk4 + 0][lr] = ax; As[lk4 + 1][lr] = ay;
        As[lk4 + 2][lr] = az; As[lk4 + 3][lr] = aw;
        Ws[lk4 + 0][lr] = wv4.x; Ws[lk4 + 1][lr] = wv4.y;
        Ws[lk4 + 2][lr] = wv4.z; Ws[lk4 + 3][lr] = wv4.w;
        __syncthreads();
        #pragma unroll
        for (int k = 0; k < 16; k++) {
            float4 a  = *(const float4*)(&As[k][ty * 4]);
            float4 bb = *(const float4*)(&Ws[k][tx * 4]);
            acc[0][0] += a.x * bb.x; acc[0][1] += a.x * bb.y; acc[0][2] += a.x * bb.z; acc[0][3] += a.x * bb.w;
            acc[1][0] += a.y * bb.x; acc[1][1] += a.y * bb.y; acc[1][2] += a.y * bb.z; acc[1][3] += a.y * bb.w;
            acc[2][0] += a.z * bb.x; acc[2][1] += a.z * bb.y; acc[2][2] += a.z * bb.z; acc[2][3] += a.z * bb.w;
            acc[3][0] += a.w * bb.x; acc[3][1] += a.w * bb.y; acc[3][2] += a.w * bb.z; acc[3][3] += a.w * bb.w;
        }
        __syncthreads();
    }
    #pragma unroll
    for (int i = 0; i < 4; i++) {
        int r = r0 + ty * 4 + i;
        #pragma unroll
        for (int j = 0; j < 4; j++) {
            int m = m0 + tx * 4 + j;
            float v = acc[i][j] + bias[m];
            if (res) v += b2f(res[(size_t)r * M + m]);
            if (!out_transpose) {
                stv(out, (size_t)r * M + m, v);
            } else {
                int t = r >> 5, bb = r & 31;
                stv(out, ((size_t)bb * T_ + t) * M + m, v);
            }
        }
    }
}

// ---------------------------------------------------------------------------
// Attention over the batch axis: one block per (t,h). Q,K,V (T,B,F) bf16.
__global__ __launch_bounds__(256) void attention(const bfu* __restrict__ Q,
                                                 const bfu* __restrict__ K,
                                                 const bfu* __restrict__ V,
                                                 bfu* __restrict__ O) {
    __shared__ float qs[32][65], ks[32][65], vs[32][65], ps[32][33];
    int t = blockIdx.x, h = blockIdx.y;
    int tid = threadIdx.x;
    size_t base = (size_t)t * B_ * F_ + (size_t)h * 64;
    for (int i = tid * 4; i < 32 * 64; i += 1024) {
        int bb = i >> 6, d = i & 63;
        size_t idx = base + (size_t)bb * F_ + d;
        ushort4 q4 = *(const ushort4*)(Q + idx);
        ushort4 k4 = *(const ushort4*)(K + idx);
        ushort4 v4 = *(const ushort4*)(V + idx);
        qs[bb][d] = b2f(q4.x); qs[bb][d + 1] = b2f(q4.y); qs[bb][d + 2] = b2f(q4.z); qs[bb][d + 3] = b2f(q4.w);
        ks[bb][d] = b2f(k4.x); ks[bb][d + 1] = b2f(k4.y); ks[bb][d + 2] = b2f(k4.z); ks[bb][d + 3] = b2f(k4.w);
        vs[bb][d] = b2f(v4.x); vs[bb][d + 1] = b2f(v4.y); vs[bb][d + 2] = b2f(v4.z); vs[bb][d + 3] = b2f(v4.w);
    }
    __syncthreads();
    int brow = tid >> 3;
    int c0   = (tid & 7) * 4;
    float sc0 = 0.f, sc1 = 0.f, sc2 = 0.f, sc3 = 0.f;
    for (int d = 0; d < 64; d++) {
        float qv = qs[brow][d];
        sc0 += qv * ks[c0 + 0][d];
        sc1 += qv * ks[c0 + 1][d];
        sc2 += qv * ks[c0 + 2][d];
        sc3 += qv * ks[c0 + 3][d];
    }
    ps[brow][c0 + 0] = sc0 * 0.125f;
    ps[brow][c0 + 1] = sc1 * 0.125f;
    ps[brow][c0 + 2] = sc2 * 0.125f;
    ps[brow][c0 + 3] = sc3 * 0.125f;
    __syncthreads();
    if (tid < 32) {
        float mx = -1e30f;
        for (int c = 0; c < 32; c++) mx = fmaxf(mx, ps[tid][c]);
        float sum = 0.f;
        for (int c = 0; c < 32; c++) { float e = expf(ps[tid][c] - mx); ps[tid][c] = e; sum += e; }
        float inv = 1.0f / sum;
        for (int c = 0; c < 32; c++) ps[tid][c] *= inv;
    }
    __syncthreads();
    int d0 = (tid & 7) * 8;
    float ov[8] = {};
    for (int c = 0; c < 32; c++) {
        float p = ps[brow][c];
        #pragma unroll
        for (int j = 0; j < 8; j++) ov[j] += p * vs[c][d0 + j];
    }
    #pragma unroll
    for (int j = 0; j < 8; j++)
        O[base + (size_t)brow * F_ + d0 + j] = f2b(ov[j]);
}

// ---------------------------------------------------------------------------
extern "C" void kernel_launch(void* const* d_in, const int* in_sizes, int n_in,
                              void* d_out, int out_size, void* d_ws, size_t ws_size,
                              hipStream_t stream) {
    const float* x     = (const float*)d_in[0];
    const float* dw1_w = (const float*)d_in[1];
    const float* dw1_b = (const float*)d_in[2];
    const float* pw1_w = (const float*)d_in[3];
    const float* pw1_b = (const float*)d_in[4];
    const float* dw2_w = (const float*)d_in[5];
    const float* dw2_b = (const float*)d_in[6];
    const float* pw2_w = (const float*)d_in[7];
    const float* pw2_b = (const float*)d_in[8];
    const float* wq = (const float*)d_in[9];   const float* bq = (const float*)d_in[10];
    const float* wk = (const float*)d_in[11];  const float* bk = (const float*)d_in[12];
    const float* wv = (const float*)d_in[13];  const float* bv = (const float*)d_in[14];
    const float* wp = (const float*)d_in[15];  const float* bp = (const float*)d_in[16];
    const float* ffw = (const float*)d_in[17]; const float* ffb = (const float*)d_in[18];
    float* out = (float*)d_out;

    const size_t SZ = (size_t)B_ * F_ * T_;   // 33,554,432 elems (64 MB bf16)
    // Layout: stats (small) first, then 5 bf16 buffers. Total ~321 MB.
    float* stats = (float*)d_ws;              // 4096 fp32
    bfu* bufX = (bfu*)d_ws + (1 << 19);       // +1 MB: act (B,F,T); later Q
    bfu* bufC = bufX + SZ;                    // dwconv scratch; later xa (T,B,F)
    bfu* bufY = bufC + SZ;                    // yln (T,B,F); later attn O
    bfu* bufK = bufY + SZ;
    bfu* bufV = bufK + SZ;

    dim3 bt(32, 8);
    const int R = T_ * B_;  // 65536 attention rows

    // pos-enc + transpose to (B,E,T)
    pos_transpose<<<dim3(T_ / 32, E_ / 32, B_), bt, 0, stream>>>(x, bufX);

    auto statsPerB = [&](const bfu* src) {
        zero_kernel<<<16, 256, 0, stream>>>(stats, 4096);
        ln_stats<<<dim3(64, B_), 256, 0, stream>>>(src, stats, F_ * T_, 64);
    };

    // conv1: x = pw1(dw1(ln(x0)))
    statsPerB(bufX);
    dwconv_ln<<<dim3(T_ / 256, F_, B_), 256, 0, stream>>>(bufX, stats, dw1_w, dw1_b, bufC);
    gemm_pw<<<dim3(T_ / 64, F_ / 64, B_), 256, 0, stream>>>(pw1_w, bufC, pw1_b, nullptr, bufX);

    // conv loop (shared dw2/pw2 weights), residual fused into gemm epilogue
    for (int it = 0; it < 3; ++it) {
        statsPerB(bufX);
        dwconv_ln<<<dim3(T_ / 256, F_, B_), 256, 0, stream>>>(bufX, stats, dw2_w, dw2_b, bufC);
        gemm_pw<<<dim3(T_ / 64, F_ / 64, B_), 256, 0, stream>>>(pw2_w, bufC, pw2_b, bufX, bufX);
    }

    // transpose to (T,B,F): xa = x (bufC), yln = ln(x) (bufY)
    statsPerB(bufX);
    transpose_ln<<<dim3(T_ / 32, F_ / 32, B_), bt, 0, stream>>>(bufX, stats, bufC, bufY);

    // QKV projections (bufX dead -> reuse for Q)
    gemm_nt<bfu><<<dim3(F_ / 64, R / 64), 256, 0, stream>>>(bufY, wq, bq, nullptr, bufX, nullptr, 0.f, 0);
    gemm_nt<bfu><<<dim3(F_ / 64, R / 64), 256, 0, stream>>>(bufY, wk, bk, nullptr, bufK, nullptr, 0.f, 0);
    gemm_nt<bfu><<<dim3(F_ / 64, R / 64), 256, 0, stream>>>(bufY, wv, bv, nullptr, bufV, nullptr, 0.f, 0);

    // attention across batch axis (yln dead -> bufY holds O)
    attention<<<dim3(T_, H_), 256, 0, stream>>>(bufX, bufK, bufV, bufY);

    // output projection + residual (xa in bufC): xnew -> bufK (K dead)
    gemm_nt<bfu><<<dim3(F_ / 64, R / 64), 256, 0, stream>>>(bufY, wp, bp, bufC, bufK, nullptr, 0.f, 0);

    // final LN per t over (B,F) = 16384 contiguous elems per group
    zero_kernel<<<16, 256, 0, stream>>>(stats, 4096);
    ln_stats<<<dim3(1, T_), 256, 0, stream>>>(bufK, stats, B_ * F_, 1);

    // FF gemm: fused LN on A, residual = xnew, fp32 (B,T,F) transposed output
    gemm_nt<float><<<dim3(F_ / 64, R / 64), 256, 0, stream>>>(bufK, ffw, ffb, bufK, out, stats,
                                                              1.0f / (float)(B_ * F_), 1);
}